// Round 7
// baseline (392.288 us; speedup 1.0000x reference)
//
#include <hip/hip_runtime.h>
#include <hip/hip_bf16.h>
#include <hip/hip_fp16.h>
#include <math.h>

#define DF 128          // feature dim
#define NLAYERS 5

typedef __attribute__((ext_vector_type(8))) short bf16x8;
typedef __attribute__((ext_vector_type(4))) short short4v;
typedef __attribute__((ext_vector_type(4))) float f32x4;

// RTNE float -> bf16 bit pattern
__device__ inline unsigned short f2bf(float f) {
    unsigned u = __float_as_uint(f);
    u += 0x7FFF + ((u >> 16) & 1u);
    return (unsigned short)(u >> 16);
}
__device__ inline float bf2f(unsigned short s) {
    return __uint_as_float(((unsigned)s) << 16);
}

// packed fp16 max on raw bits (ROCm 7.2 lacks a viable fp16 __hmax2 overload)
__device__ inline unsigned pkmax(unsigned a, unsigned b) {
    unsigned d;
    asm("v_pk_max_f16 %0, %1, %2" : "=v"(d) : "v"(a), "v"(b));
    return d;
}
__device__ inline float h2f(unsigned short u) {
    __half_raw r; r.x = u;
    return __half2float(__half(r));
}
__device__ inline float silu(float v) {
    return v * (1.0f / (1.0f + __expf(-v)));
}

// ---------------- CSR build ----------------

__global__ void hist_rank_kernel(const int* __restrict__ dst, int* __restrict__ cnt,
        int* __restrict__ rank, int E) {
    int i = blockIdx.x * blockDim.x + threadIdx.x;
    if (i < E) rank[i] = atomicAdd(&cnt[dst[i]], 1);
}

__global__ __launch_bounds__(256) void partial_sum_kernel(const int* __restrict__ cnt,
        int* __restrict__ bsum, int n) {
    __shared__ int red[256];
    int t = threadIdx.x;
    int i = blockIdx.x * 256 + t;
    red[t] = (i < n) ? cnt[i] : 0;
    __syncthreads();
    for (int d = 128; d > 0; d >>= 1) {
        if (t < d) red[t] += red[t + d];
        __syncthreads();
    }
    if (t == 0) bsum[blockIdx.x] = red[0];
}

__global__ __launch_bounds__(1024) void scan_bsums_kernel(const int* __restrict__ bsum,
        int* __restrict__ bbase, int nb) {
    __shared__ int s[1024];
    int t = threadIdx.x;
    int v = (t < nb) ? bsum[t] : 0;
    s[t] = v;
    __syncthreads();
    for (int d = 1; d < 1024; d <<= 1) {
        int u = (t >= d) ? s[t - d] : 0;
        __syncthreads();
        s[t] += u;
        __syncthreads();
    }
    if (t < nb) bbase[t] = s[t] - v;   // exclusive
}

__global__ __launch_bounds__(256) void scan_scatter_kernel(const int* __restrict__ cnt,
        const int* __restrict__ bbase, int* __restrict__ off, int n, int E) {
    __shared__ int s[256];
    int t = threadIdx.x;
    int i = blockIdx.x * 256 + t;
    int v = (i < n) ? cnt[i] : 0;
    s[t] = v;
    __syncthreads();
    for (int d = 1; d < 256; d <<= 1) {
        int u = (t >= d) ? s[t - d] : 0;
        __syncthreads();
        s[t] += u;
        __syncthreads();
    }
    int excl = s[t] - v + bbase[blockIdx.x];
    if (i < n) off[i] = excl;
    if (blockIdx.x == 0 && t == 0) off[n] = E;
}

__global__ void fill_kernel(const int* __restrict__ src, const int* __restrict__ dst,
        const int* __restrict__ off, const int* __restrict__ rank,
        int* __restrict__ csr, int E) {
    int i = blockIdx.x * blockDim.x + threadIdx.x;
    if (i < E) csr[off[dst[i]] + rank[i]] = src[i];
}

// ---------------- split prep: fp32 -> (bf16 hi, bf16 lo) ----------------

__global__ __launch_bounds__(256) void split_kernel(const float* __restrict__ in,
        short* __restrict__ hi, short* __restrict__ lo, int total4) {
    int i = blockIdx.x * 256 + threadIdx.x;
    if (i >= total4) return;
    float4 v = reinterpret_cast<const float4*>(in)[i];
    short4v h, l;
    {
        unsigned short a = f2bf(v.x); h.x = (short)a; l.x = (short)f2bf(v.x - bf2f(a));
        unsigned short b = f2bf(v.y); h.y = (short)b; l.y = (short)f2bf(v.y - bf2f(b));
        unsigned short c = f2bf(v.z); h.z = (short)c; l.z = (short)f2bf(v.z - bf2f(c));
        unsigned short d = f2bf(v.w); h.w = (short)d; l.w = (short)f2bf(v.w - bf2f(d));
    }
    reinterpret_cast<short4v*>(hi)[i] = h;
    reinterpret_cast<short4v*>(lo)[i] = l;
}

// ---------------- layer-0 GEMM via MFMA (x from global split buffers) ----------

__global__ __launch_bounds__(256, 3) void gemm_mfma_kernel(
        const short* __restrict__ xhi, const short* __restrict__ xlo,
        const short* __restrict__ whi, const short* __restrict__ wlo,
        const float* __restrict__ bias, __half* __restrict__ h, int n) {
    int wave = threadIdx.x >> 6;
    int lane = threadIdx.x & 63;
    int wm = wave >> 1;
    int wn = wave & 1;
    int m0 = blockIdx.x * 64 + wm * 32;
    int n0 = wn * 64;
    int lr = lane & 15;
    int lk = lane >> 4;

    f32x4 acc[2][4];
#pragma unroll
    for (int mt = 0; mt < 2; ++mt)
#pragma unroll
        for (int nt = 0; nt < 4; ++nt) {
            float bv = bias[n0 + nt * 16 + lr];
            acc[mt][nt] = (f32x4){bv, bv, bv, bv};
        }

    int rowA0 = min(m0 + lr, n - 1);
    int rowA1 = min(m0 + 16 + lr, n - 1);

#pragma unroll
    for (int ks = 0; ks < 4; ++ks) {
        int ko = ks * 32 + lk * 8;
        bf16x8 a0h = *(const bf16x8*)(xhi + (size_t)rowA0 * DF + ko);
        bf16x8 a0l = *(const bf16x8*)(xlo + (size_t)rowA0 * DF + ko);
        bf16x8 a1h = *(const bf16x8*)(xhi + (size_t)rowA1 * DF + ko);
        bf16x8 a1l = *(const bf16x8*)(xlo + (size_t)rowA1 * DF + ko);
#pragma unroll
        for (int nt = 0; nt < 4; ++nt) {
            int ncol = n0 + nt * 16 + lr;
            bf16x8 bh = *(const bf16x8*)(whi + ncol * DF + ko);
            bf16x8 bl = *(const bf16x8*)(wlo + ncol * DF + ko);
            acc[0][nt] = __builtin_amdgcn_mfma_f32_16x16x32_bf16(a0h, bh, acc[0][nt], 0, 0, 0);
            acc[0][nt] = __builtin_amdgcn_mfma_f32_16x16x32_bf16(a0l, bh, acc[0][nt], 0, 0, 0);
            acc[0][nt] = __builtin_amdgcn_mfma_f32_16x16x32_bf16(a0h, bl, acc[0][nt], 0, 0, 0);
            acc[1][nt] = __builtin_amdgcn_mfma_f32_16x16x32_bf16(a1h, bh, acc[1][nt], 0, 0, 0);
            acc[1][nt] = __builtin_amdgcn_mfma_f32_16x16x32_bf16(a1l, bh, acc[1][nt], 0, 0, 0);
            acc[1][nt] = __builtin_amdgcn_mfma_f32_16x16x32_bf16(a1h, bl, acc[1][nt], 0, 0, 0);
        }
    }

#pragma unroll
    for (int mt = 0; mt < 2; ++mt) {
        int rbase = m0 + mt * 16 + lk * 4;
#pragma unroll
        for (int j = 0; j < 4; ++j) {
            int r = rbase + j;
            if (r < n) {
#pragma unroll
                for (int nt = 0; nt < 4; ++nt)
                    h[(size_t)r * DF + n0 + nt * 16 + lr] = __float2half(acc[mt][nt][j]);
            }
        }
    }
}

// ---------------- fused: agg(h_in) -> SiLU -> split(LDS) -> gemm -> h_out ------
// Block = 64 nodes. Agg: 4 waves x 16 nodes; per node, 16 lanes x 16B cover the
// 256B fp16 row, quarters q=0..3 take 4 edges at once; 2-deep unroll = 8 rows
// in flight; duplicate-safe tail via min(k+q, end-1). Handoff via XOR-swizzled
// LDS (A-fragment ds_read_b128 conflict-free). Gemm: same MFMA tile as layer 0.

__global__ __launch_bounds__(256) void fused_agg_gemm_kernel(
        const __half* __restrict__ hin,
        const int* __restrict__ off, const int* __restrict__ csr,
        const short* __restrict__ whi, const short* __restrict__ wlo,
        const float* __restrict__ bias, __half* __restrict__ hout, int n) {
    __shared__ __align__(16) short xh[64 * DF];
    __shared__ __align__(16) short xl[64 * DF];

    int wave = threadIdx.x >> 6;
    int lane = threadIdx.x & 63;
    int q = lane >> 4;           // row-quarter (which of 4 edges)
    int c = lane & 15;           // 16B column within 256B row
    int nodebase = blockIdx.x * 64;

    // ---- agg phase ----
    for (int i = 0; i < 16; ++i) {
        int r = wave * 16 + i;
        int node = nodebase + r;
        if (node >= n) break;
        int beg = off[node];
        int end = off[node + 1];
        unsigned m0 = 0xFC00FC00u, m1 = m0, m2 = m0, m3 = m0;
        if (beg < end) {
            for (int k = beg; k < end; k += 8) {
                int ka = min(k + q, end - 1);
                int kb = min(k + 4 + q, end - 1);
                uint4 a = *(const uint4*)((const char*)hin + ((size_t)csr[ka] << 8) + (c << 4));
                uint4 b = *(const uint4*)((const char*)hin + ((size_t)csr[kb] << 8) + (c << 4));
                m0 = pkmax(m0, pkmax(a.x, b.x));
                m1 = pkmax(m1, pkmax(a.y, b.y));
                m2 = pkmax(m2, pkmax(a.z, b.z));
                m3 = pkmax(m3, pkmax(a.w, b.w));
            }
            m0 = pkmax(m0, (unsigned)__shfl_xor((int)m0, 16));
            m0 = pkmax(m0, (unsigned)__shfl_xor((int)m0, 32));
            m1 = pkmax(m1, (unsigned)__shfl_xor((int)m1, 16));
            m1 = pkmax(m1, (unsigned)__shfl_xor((int)m1, 32));
            m2 = pkmax(m2, (unsigned)__shfl_xor((int)m2, 16));
            m2 = pkmax(m2, (unsigned)__shfl_xor((int)m2, 32));
            m3 = pkmax(m3, (unsigned)__shfl_xor((int)m3, 16));
            m3 = pkmax(m3, (unsigned)__shfl_xor((int)m3, 32));
        }
        if (q == 0) {
            float f[8];
            f[0] = h2f((unsigned short)(m0 & 0xFFFF)); f[1] = h2f((unsigned short)(m0 >> 16));
            f[2] = h2f((unsigned short)(m1 & 0xFFFF)); f[3] = h2f((unsigned short)(m1 >> 16));
            f[4] = h2f((unsigned short)(m2 & 0xFFFF)); f[5] = h2f((unsigned short)(m2 >> 16));
            f[6] = h2f((unsigned short)(m3 & 0xFFFF)); f[7] = h2f((unsigned short)(m3 >> 16));
            bf16x8 hv, lv;
#pragma unroll
            for (int j = 0; j < 8; ++j) {
                float v = (beg == end) ? 0.0f : silu(f[j]);
                unsigned short a = f2bf(v);
                hv[j] = (short)a;
                lv[j] = (short)f2bf(v - bf2f(a));
            }
            int bc = (c << 4) ^ ((r & 7) << 4);
            *(bf16x8*)((char*)xh + r * 256 + bc) = hv;
            *(bf16x8*)((char*)xl + r * 256 + bc) = lv;
        }
    }
    __syncthreads();

    // ---- gemm phase ----
    int wm = wave >> 1;
    int wn = wave & 1;
    int n0 = wn * 64;
    int lr = lane & 15;
    int lk = lane >> 4;

    f32x4 acc[2][4];
#pragma unroll
    for (int mt = 0; mt < 2; ++mt)
#pragma unroll
        for (int nt = 0; nt < 4; ++nt) {
            float bv = bias[n0 + nt * 16 + lr];
            acc[mt][nt] = (f32x4){bv, bv, bv, bv};
        }

    int row0 = wm * 32 + lr;
    int row1 = row0 + 16;

#pragma unroll
    for (int ks = 0; ks < 4; ++ks) {
        int bo = ks * 64 + lk * 16;
        bf16x8 a0h = *(const bf16x8*)((char*)xh + row0 * 256 + (bo ^ ((row0 & 7) << 4)));
        bf16x8 a0l = *(const bf16x8*)((char*)xl + row0 * 256 + (bo ^ ((row0 & 7) << 4)));
        bf16x8 a1h = *(const bf16x8*)((char*)xh + row1 * 256 + (bo ^ ((row1 & 7) << 4)));
        bf16x8 a1l = *(const bf16x8*)((char*)xl + row1 * 256 + (bo ^ ((row1 & 7) << 4)));
        int ko = ks * 32 + lk * 8;
#pragma unroll
        for (int nt = 0; nt < 4; ++nt) {
            int ncol = n0 + nt * 16 + lr;
            bf16x8 bh = *(const bf16x8*)(whi + ncol * DF + ko);
            bf16x8 bl = *(const bf16x8*)(wlo + ncol * DF + ko);
            acc[0][nt] = __builtin_amdgcn_mfma_f32_16x16x32_bf16(a0h, bh, acc[0][nt], 0, 0, 0);
            acc[0][nt] = __builtin_amdgcn_mfma_f32_16x16x32_bf16(a0l, bh, acc[0][nt], 0, 0, 0);
            acc[0][nt] = __builtin_amdgcn_mfma_f32_16x16x32_bf16(a0h, bl, acc[0][nt], 0, 0, 0);
            acc[1][nt] = __builtin_amdgcn_mfma_f32_16x16x32_bf16(a1h, bh, acc[1][nt], 0, 0, 0);
            acc[1][nt] = __builtin_amdgcn_mfma_f32_16x16x32_bf16(a1l, bh, acc[1][nt], 0, 0, 0);
            acc[1][nt] = __builtin_amdgcn_mfma_f32_16x16x32_bf16(a1h, bl, acc[1][nt], 0, 0, 0);
        }
    }

#pragma unroll
    for (int mt = 0; mt < 2; ++mt) {
        int rbase = nodebase + wm * 32 + mt * 16 + lk * 4;
#pragma unroll
        for (int j = 0; j < 4; ++j) {
            int r = rbase + j;
            if (r < n) {
#pragma unroll
                for (int nt = 0; nt < 4; ++nt)
                    hout[(size_t)r * DF + n0 + nt * 16 + lr] = __float2half(acc[mt][nt][j]);
            }
        }
    }
}

// ---------------- final aggregation (no SiLU, fp32 out) ----------------

__global__ __launch_bounds__(256) void agg_final_kernel(const __half* __restrict__ hin,
        const int* __restrict__ off, const int* __restrict__ csr,
        float* __restrict__ out, int n) {
    int wave = threadIdx.x >> 6;
    int lane = threadIdx.x & 63;
    int q = lane >> 4;
    int c = lane & 15;
    int nodebase = blockIdx.x * 64;

    for (int i = 0; i < 16; ++i) {
        int node = nodebase + wave * 16 + i;
        if (node >= n) break;
        int beg = off[node];
        int end = off[node + 1];
        unsigned m0 = 0xFC00FC00u, m1 = m0, m2 = m0, m3 = m0;
        if (beg < end) {
            for (int k = beg; k < end; k += 8) {
                int ka = min(k + q, end - 1);
                int kb = min(k + 4 + q, end - 1);
                uint4 a = *(const uint4*)((const char*)hin + ((size_t)csr[ka] << 8) + (c << 4));
                uint4 b = *(const uint4*)((const char*)hin + ((size_t)csr[kb] << 8) + (c << 4));
                m0 = pkmax(m0, pkmax(a.x, b.x));
                m1 = pkmax(m1, pkmax(a.y, b.y));
                m2 = pkmax(m2, pkmax(a.z, b.z));
                m3 = pkmax(m3, pkmax(a.w, b.w));
            }
            m0 = pkmax(m0, (unsigned)__shfl_xor((int)m0, 16));
            m0 = pkmax(m0, (unsigned)__shfl_xor((int)m0, 32));
            m1 = pkmax(m1, (unsigned)__shfl_xor((int)m1, 16));
            m1 = pkmax(m1, (unsigned)__shfl_xor((int)m1, 32));
            m2 = pkmax(m2, (unsigned)__shfl_xor((int)m2, 16));
            m2 = pkmax(m2, (unsigned)__shfl_xor((int)m2, 32));
            m3 = pkmax(m3, (unsigned)__shfl_xor((int)m3, 16));
            m3 = pkmax(m3, (unsigned)__shfl_xor((int)m3, 32));
        }
        if (q == 0) {
            float f[8];
            f[0] = h2f((unsigned short)(m0 & 0xFFFF)); f[1] = h2f((unsigned short)(m0 >> 16));
            f[2] = h2f((unsigned short)(m1 & 0xFFFF)); f[3] = h2f((unsigned short)(m1 >> 16));
            f[4] = h2f((unsigned short)(m2 & 0xFFFF)); f[5] = h2f((unsigned short)(m2 >> 16));
            f[6] = h2f((unsigned short)(m3 & 0xFFFF)); f[7] = h2f((unsigned short)(m3 >> 16));
            if (beg == end) {
#pragma unroll
                for (int j = 0; j < 8; ++j) f[j] = 0.0f;
            }
            float4* o = (float4*)(out + (size_t)node * DF + c * 8);
            o[0] = make_float4(f[0], f[1], f[2], f[3]);
            o[1] = make_float4(f[4], f[5], f[6], f[7]);
        }
    }
}

// ---------------- Launch ----------------

extern "C" void kernel_launch(void* const* d_in, const int* in_sizes, int n_in,
                              void* d_out, int out_size, void* d_ws, size_t ws_size,
                              hipStream_t stream) {
    const float* x  = (const float*)d_in[0];
    const int*   ei = (const int*)d_in[1];
    const float* Ws = (const float*)d_in[2];
    const float* bs = (const float*)d_in[3];
    float* out = (float*)d_out;

    int N = in_sizes[0] / DF;
    int E = in_sizes[1] / 2;
    const int* src = ei;
    const int* dst = ei + E;

    char* w = (char*)d_ws;
    auto carve = [&](size_t bytes) {
        char* p = w;
        w += (bytes + 255) & ~(size_t)255;
        return p;
    };
    int nb = (N + 255) / 256;
    int*    cnt   = (int*)carve((size_t)(N + 1) * sizeof(int));
    int*    off   = (int*)carve((size_t)(N + 1) * sizeof(int));
    int*    bsum  = (int*)carve((size_t)nb * sizeof(int));
    int*    bbase = (int*)carve((size_t)nb * sizeof(int));
    int*    rank  = (int*)carve((size_t)E * sizeof(int));
    int*    csr   = (int*)carve((size_t)E * sizeof(int));
    __half* hA    = (__half*)carve((size_t)N * DF * sizeof(__half));
    __half* hB    = (__half*)carve((size_t)N * DF * sizeof(__half));
    short*  xhi   = (short*)carve((size_t)N * DF * sizeof(short));
    short*  xlo   = (short*)carve((size_t)N * DF * sizeof(short));
    short*  whi   = (short*)carve((size_t)NLAYERS * DF * DF * sizeof(short));
    short*  wlo   = (short*)carve((size_t)NLAYERS * DF * DF * sizeof(short));

    // ---- CSR build (once) ----
    hipMemsetAsync(cnt, 0, (size_t)N * sizeof(int), stream);
    hist_rank_kernel<<<(E + 255) / 256, 256, 0, stream>>>(dst, cnt, rank, E);
    partial_sum_kernel<<<nb, 256, 0, stream>>>(cnt, bsum, N);
    scan_bsums_kernel<<<1, 1024, 0, stream>>>(bsum, bbase, nb);
    scan_scatter_kernel<<<nb, 256, 0, stream>>>(cnt, bbase, off, N, E);
    fill_kernel<<<(E + 255) / 256, 256, 0, stream>>>(src, dst, off, rank, csr, E);

    // ---- split preps ----
    int xt4 = N * DF / 4;
    split_kernel<<<(xt4 + 255) / 256, 256, 0, stream>>>(x, xhi, xlo, xt4);
    int wt4 = NLAYERS * DF * DF / 4;
    split_kernel<<<(wt4 + 255) / 256, 256, 0, stream>>>(Ws, whi, wlo, wt4);

    int nblocks = (N + 63) / 64;

    // layer 0 gemm: x -> hA
    gemm_mfma_kernel<<<nblocks, 256, 0, stream>>>(xhi, xlo, whi, wlo, bs, hA, N);

    // layers 1..4: fused agg(prev h) + gemm -> next h  (ping-pong hA/hB)
    __half* hin = hA;
    __half* hout = hB;
    for (int layer = 1; layer < NLAYERS; ++layer) {
        const short* whl = whi + (size_t)layer * DF * DF;
        const short* wll = wlo + (size_t)layer * DF * DF;
        const float* bl = bs + (size_t)layer * DF;
        fused_agg_gemm_kernel<<<nblocks, 256, 0, stream>>>(
            hin, off, csr, whl, wll, bl, hout, N);
        __half* t = hin; hin = hout; hout = t;
    }

    // final aggregation of layer-4 output (no SiLU), fp32 to d_out
    agg_final_kernel<<<nblocks, 256, 0, stream>>>(hin, off, csr, out, N);
}

// Round 8
// 346.749 us; speedup vs baseline: 1.1313x; 1.1313x over previous
//
#include <hip/hip_runtime.h>
#include <hip/hip_bf16.h>
#include <hip/hip_fp16.h>
#include <math.h>

#define DF 128          // feature dim
#define NLAYERS 5

typedef __attribute__((ext_vector_type(8))) short bf16x8;
typedef __attribute__((ext_vector_type(4))) short short4v;
typedef __attribute__((ext_vector_type(4))) float f32x4;

// RTNE float -> bf16 bit pattern
__device__ inline unsigned short f2bf(float f) {
    unsigned u = __float_as_uint(f);
    u += 0x7FFF + ((u >> 16) & 1u);
    return (unsigned short)(u >> 16);
}
__device__ inline float bf2f(unsigned short s) {
    return __uint_as_float(((unsigned)s) << 16);
}

// packed fp16 max on raw bits (ROCm 7.2 lacks a viable fp16 __hmax2 overload)
__device__ inline unsigned pkmax(unsigned a, unsigned b) {
    unsigned d;
    asm("v_pk_max_f16 %0, %1, %2" : "=v"(d) : "v"(a), "v"(b));
    return d;
}
__device__ inline float h2f(unsigned short u) {
    __half_raw r; r.x = u;
    return __half2float(__half(r));
}
__device__ inline float silu(float v) {
    return v * (1.0f / (1.0f + __expf(-v)));
}

// split 8 consecutive floats into bf16 hi/lo fragments
__device__ inline void split8(const float* p, bf16x8& hi, bf16x8& lo) {
    float4 v0 = *reinterpret_cast<const float4*>(p);
    float4 v1 = *reinterpret_cast<const float4*>(p + 4);
    float f[8] = {v0.x, v0.y, v0.z, v0.w, v1.x, v1.y, v1.z, v1.w};
#pragma unroll
    for (int j = 0; j < 8; ++j) {
        unsigned short a = f2bf(f[j]);
        hi[j] = (short)a;
        lo[j] = (short)f2bf(f[j] - bf2f(a));
    }
}

// ---------------- prep: histogram+rank (blocks [0,nbE)) | split W (rest) -----

__global__ __launch_bounds__(256) void prep_kernel(const int* __restrict__ dst,
        int* __restrict__ cnt, int* __restrict__ rank, int E, int nbE,
        const float* __restrict__ Ws, short* __restrict__ whi,
        short* __restrict__ wlo, int wt4) {
    int b = blockIdx.x;
    int t = threadIdx.x;
    if (b < nbE) {
        int i = b * 256 + t;
        if (i < E) rank[i] = atomicAdd(&cnt[dst[i]], 1);
    } else {
        int i = (b - nbE) * 256 + t;
        if (i < wt4) {
            float4 v = reinterpret_cast<const float4*>(Ws)[i];
            short4v h, l;
            unsigned short a = f2bf(v.x); h.x = (short)a; l.x = (short)f2bf(v.x - bf2f(a));
            unsigned short bq = f2bf(v.y); h.y = (short)bq; l.y = (short)f2bf(v.y - bf2f(bq));
            unsigned short c = f2bf(v.z); h.z = (short)c; l.z = (short)f2bf(v.z - bf2f(c));
            unsigned short d = f2bf(v.w); h.w = (short)d; l.w = (short)f2bf(v.w - bf2f(d));
            reinterpret_cast<short4v*>(whi)[i] = h;
            reinterpret_cast<short4v*>(wlo)[i] = l;
        }
    }
}

// ---------------- CSR scan chain ----------------

__global__ __launch_bounds__(256) void partial_sum_kernel(const int* __restrict__ cnt,
        int* __restrict__ bsum, int n) {
    __shared__ int red[256];
    int t = threadIdx.x;
    int i = blockIdx.x * 256 + t;
    red[t] = (i < n) ? cnt[i] : 0;
    __syncthreads();
    for (int d = 128; d > 0; d >>= 1) {
        if (t < d) red[t] += red[t + d];
        __syncthreads();
    }
    if (t == 0) bsum[blockIdx.x] = red[0];
}

__global__ __launch_bounds__(1024) void scan_bsums_kernel(const int* __restrict__ bsum,
        int* __restrict__ bbase, int nb) {
    __shared__ int s[1024];
    int t = threadIdx.x;
    int v = (t < nb) ? bsum[t] : 0;
    s[t] = v;
    __syncthreads();
    for (int d = 1; d < 1024; d <<= 1) {
        int u = (t >= d) ? s[t - d] : 0;
        __syncthreads();
        s[t] += u;
        __syncthreads();
    }
    if (t < nb) bbase[t] = s[t] - v;   // exclusive
}

__global__ __launch_bounds__(256) void scan_scatter_kernel(const int* __restrict__ cnt,
        const int* __restrict__ bbase, int* __restrict__ off, int n, int E) {
    __shared__ int s[256];
    int t = threadIdx.x;
    int i = blockIdx.x * 256 + t;
    int v = (i < n) ? cnt[i] : 0;
    s[t] = v;
    __syncthreads();
    for (int d = 1; d < 256; d <<= 1) {
        int u = (t >= d) ? s[t - d] : 0;
        __syncthreads();
        s[t] += u;
        __syncthreads();
    }
    int excl = s[t] - v + bbase[blockIdx.x];
    if (i < n) off[i] = excl;
    if (blockIdx.x == 0 && t == 0) off[n] = E;
}

__global__ void fill_kernel(const int* __restrict__ src, const int* __restrict__ dst,
        const int* __restrict__ off, const int* __restrict__ rank,
        int* __restrict__ csr, int E) {
    int i = blockIdx.x * blockDim.x + threadIdx.x;
    if (i < E) csr[off[dst[i]] + rank[i]] = src[i];
}

// ---------------- layer-0 GEMM via MFMA (inline split of fp32 x) ----------

__global__ __launch_bounds__(256, 3) void gemm0_kernel(
        const float* __restrict__ x,
        const short* __restrict__ whi, const short* __restrict__ wlo,
        const float* __restrict__ bias, __half* __restrict__ h, int n) {
    int wave = threadIdx.x >> 6;
    int lane = threadIdx.x & 63;
    int wm = wave >> 1;
    int wn = wave & 1;
    int m0 = blockIdx.x * 64 + wm * 32;
    int n0 = wn * 64;
    int lr = lane & 15;
    int lk = lane >> 4;

    f32x4 acc[2][4];
#pragma unroll
    for (int mt = 0; mt < 2; ++mt)
#pragma unroll
        for (int nt = 0; nt < 4; ++nt) {
            float bv = bias[n0 + nt * 16 + lr];
            acc[mt][nt] = (f32x4){bv, bv, bv, bv};
        }

    int rowA0 = min(m0 + lr, n - 1);
    int rowA1 = min(m0 + 16 + lr, n - 1);

#pragma unroll
    for (int ks = 0; ks < 4; ++ks) {
        int ko = ks * 32 + lk * 8;
        bf16x8 a0h, a0l, a1h, a1l;
        split8(x + (size_t)rowA0 * DF + ko, a0h, a0l);
        split8(x + (size_t)rowA1 * DF + ko, a1h, a1l);
#pragma unroll
        for (int nt = 0; nt < 4; ++nt) {
            int ncol = n0 + nt * 16 + lr;
            bf16x8 bh = *(const bf16x8*)(whi + ncol * DF + ko);
            bf16x8 bl = *(const bf16x8*)(wlo + ncol * DF + ko);
            acc[0][nt] = __builtin_amdgcn_mfma_f32_16x16x32_bf16(a0h, bh, acc[0][nt], 0, 0, 0);
            acc[0][nt] = __builtin_amdgcn_mfma_f32_16x16x32_bf16(a0l, bh, acc[0][nt], 0, 0, 0);
            acc[0][nt] = __builtin_amdgcn_mfma_f32_16x16x32_bf16(a0h, bl, acc[0][nt], 0, 0, 0);
            acc[1][nt] = __builtin_amdgcn_mfma_f32_16x16x32_bf16(a1h, bh, acc[1][nt], 0, 0, 0);
            acc[1][nt] = __builtin_amdgcn_mfma_f32_16x16x32_bf16(a1l, bh, acc[1][nt], 0, 0, 0);
            acc[1][nt] = __builtin_amdgcn_mfma_f32_16x16x32_bf16(a1h, bl, acc[1][nt], 0, 0, 0);
        }
    }

#pragma unroll
    for (int mt = 0; mt < 2; ++mt) {
        int rbase = m0 + mt * 16 + lk * 4;
#pragma unroll
        for (int j = 0; j < 4; ++j) {
            int r = rbase + j;
            if (r < n) {
#pragma unroll
                for (int nt = 0; nt < 4; ++nt)
                    h[(size_t)r * DF + n0 + nt * 16 + lr] = __float2half(acc[mt][nt][j]);
            }
        }
    }
}

// ---------------- GEMM via MFMA (bf16 hi/lo inputs from agg) ----------

__global__ __launch_bounds__(256, 3) void gemm_mfma_kernel(
        const short* __restrict__ xhi, const short* __restrict__ xlo,
        const short* __restrict__ whi, const short* __restrict__ wlo,
        const float* __restrict__ bias, __half* __restrict__ h, int n) {
    int wave = threadIdx.x >> 6;
    int lane = threadIdx.x & 63;
    int wm = wave >> 1;
    int wn = wave & 1;
    int m0 = blockIdx.x * 64 + wm * 32;
    int n0 = wn * 64;
    int lr = lane & 15;
    int lk = lane >> 4;

    f32x4 acc[2][4];
#pragma unroll
    for (int mt = 0; mt < 2; ++mt)
#pragma unroll
        for (int nt = 0; nt < 4; ++nt) {
            float bv = bias[n0 + nt * 16 + lr];
            acc[mt][nt] = (f32x4){bv, bv, bv, bv};
        }

    int rowA0 = min(m0 + lr, n - 1);
    int rowA1 = min(m0 + 16 + lr, n - 1);

#pragma unroll
    for (int ks = 0; ks < 4; ++ks) {
        int ko = ks * 32 + lk * 8;
        bf16x8 a0h = *(const bf16x8*)(xhi + (size_t)rowA0 * DF + ko);
        bf16x8 a0l = *(const bf16x8*)(xlo + (size_t)rowA0 * DF + ko);
        bf16x8 a1h = *(const bf16x8*)(xhi + (size_t)rowA1 * DF + ko);
        bf16x8 a1l = *(const bf16x8*)(xlo + (size_t)rowA1 * DF + ko);
#pragma unroll
        for (int nt = 0; nt < 4; ++nt) {
            int ncol = n0 + nt * 16 + lr;
            bf16x8 bh = *(const bf16x8*)(whi + ncol * DF + ko);
            bf16x8 bl = *(const bf16x8*)(wlo + ncol * DF + ko);
            acc[0][nt] = __builtin_amdgcn_mfma_f32_16x16x32_bf16(a0h, bh, acc[0][nt], 0, 0, 0);
            acc[0][nt] = __builtin_amdgcn_mfma_f32_16x16x32_bf16(a0l, bh, acc[0][nt], 0, 0, 0);
            acc[0][nt] = __builtin_amdgcn_mfma_f32_16x16x32_bf16(a0h, bl, acc[0][nt], 0, 0, 0);
            acc[1][nt] = __builtin_amdgcn_mfma_f32_16x16x32_bf16(a1h, bh, acc[1][nt], 0, 0, 0);
            acc[1][nt] = __builtin_amdgcn_mfma_f32_16x16x32_bf16(a1l, bh, acc[1][nt], 0, 0, 0);
            acc[1][nt] = __builtin_amdgcn_mfma_f32_16x16x32_bf16(a1h, bl, acc[1][nt], 0, 0, 0);
        }
    }

#pragma unroll
    for (int mt = 0; mt < 2; ++mt) {
        int rbase = m0 + mt * 16 + lk * 4;
#pragma unroll
        for (int j = 0; j < 4; ++j) {
            int r = rbase + j;
            if (r < n) {
#pragma unroll
                for (int nt = 0; nt < 4; ++nt)
                    h[(size_t)r * DF + n0 + nt * 16 + lr] = __float2half(acc[mt][nt][j]);
            }
        }
    }
}

// ---------------- Aggregation (fp16 gather, 16 edges in flight per wave) ------
// One wave per node. uint2 (4 fp16)/lane, 32 lanes per 256B row, hf = edge
// parity. Main loop takes 16 edges/iteration = 8 independent gather chains per
// lane; avg degree 16 -> usually ONE iteration. Tail via duplicate-safe clamp
// (max is idempotent; clamped dupes hit the same cache line, ~free).

__global__ __launch_bounds__(256) void agg_kernel(const __half* __restrict__ hin,
        const int* __restrict__ off, const int* __restrict__ csr,
        float* __restrict__ out, short* __restrict__ ohi, short* __restrict__ olo,
        int n, int split) {
    int wid = threadIdx.x >> 6;
    int lane = threadIdx.x & 63;
    int node = blockIdx.x * 4 + wid;
    if (node >= n) return;

    int hf = lane >> 5;          // edge parity
    int l = lane & 31;           // uint2 column within 256B row
    const uint2* h2 = (const uint2*)hin;

    int beg = off[node];
    int end = off[node + 1];

    unsigned m0 = 0xFC00FC00u;   // packed {-inf,-inf}
    unsigned m1 = 0xFC00FC00u;

    int e1 = end - 1;
    for (int k = beg; k < end; k += 16) {
        int k0 = k + hf;
        int i0 = min(k0,      e1), i1 = min(k0 + 2,  e1);
        int i2 = min(k0 + 4,  e1), i3 = min(k0 + 6,  e1);
        int i4 = min(k0 + 8,  e1), i5 = min(k0 + 10, e1);
        int i6 = min(k0 + 12, e1), i7 = min(k0 + 14, e1);
        int s0 = csr[i0], s1 = csr[i1], s2 = csr[i2], s3 = csr[i3];
        int s4 = csr[i4], s5 = csr[i5], s6 = csr[i6], s7 = csr[i7];
        uint2 a0 = h2[s0 * 32 + l];
        uint2 a1 = h2[s1 * 32 + l];
        uint2 a2 = h2[s2 * 32 + l];
        uint2 a3 = h2[s3 * 32 + l];
        uint2 a4 = h2[s4 * 32 + l];
        uint2 a5 = h2[s5 * 32 + l];
        uint2 a6 = h2[s6 * 32 + l];
        uint2 a7 = h2[s7 * 32 + l];
        m0 = pkmax(m0, pkmax(pkmax(pkmax(a0.x, a1.x), pkmax(a2.x, a3.x)),
                             pkmax(pkmax(a4.x, a5.x), pkmax(a6.x, a7.x))));
        m1 = pkmax(m1, pkmax(pkmax(pkmax(a0.y, a1.y), pkmax(a2.y, a3.y)),
                             pkmax(pkmax(a4.y, a5.y), pkmax(a6.y, a7.y))));
    }

    // combine edge-parity halves (lane i <-> lane i^32)
    m0 = pkmax(m0, (unsigned)__shfl_xor((int)m0, 32));
    m1 = pkmax(m1, (unsigned)__shfl_xor((int)m1, 32));

    if (hf != 0) return;

    float f0 = h2f((unsigned short)(m0 & 0xFFFF));
    float f1 = h2f((unsigned short)(m0 >> 16));
    float f2 = h2f((unsigned short)(m1 & 0xFFFF));
    float f3 = h2f((unsigned short)(m1 >> 16));
    if (beg == end) { f0 = f1 = f2 = f3 = 0.0f; }

    if (split) {
        f0 = silu(f0); f1 = silu(f1); f2 = silu(f2); f3 = silu(f3);
        short4v hv, lv;
        unsigned short a = f2bf(f0); hv.x = (short)a; lv.x = (short)f2bf(f0 - bf2f(a));
        unsigned short b = f2bf(f1); hv.y = (short)b; lv.y = (short)f2bf(f1 - bf2f(b));
        unsigned short c = f2bf(f2); hv.z = (short)c; lv.z = (short)f2bf(f2 - bf2f(c));
        unsigned short d = f2bf(f3); hv.w = (short)d; lv.w = (short)f2bf(f3 - bf2f(d));
        *reinterpret_cast<short4v*>(ohi + (size_t)node * DF + l * 4) = hv;
        *reinterpret_cast<short4v*>(olo + (size_t)node * DF + l * 4) = lv;
    } else {
        float4 v = make_float4(f0, f1, f2, f3);
        reinterpret_cast<float4*>(out)[node * 32 + l] = v;
    }
}

// ---------------- Launch ----------------

extern "C" void kernel_launch(void* const* d_in, const int* in_sizes, int n_in,
                              void* d_out, int out_size, void* d_ws, size_t ws_size,
                              hipStream_t stream) {
    const float* x  = (const float*)d_in[0];
    const int*   ei = (const int*)d_in[1];
    const float* Ws = (const float*)d_in[2];
    const float* bs = (const float*)d_in[3];
    float* out = (float*)d_out;

    int N = in_sizes[0] / DF;
    int E = in_sizes[1] / 2;
    const int* src = ei;
    const int* dst = ei + E;

    char* w = (char*)d_ws;
    auto carve = [&](size_t bytes) {
        char* p = w;
        w += (bytes + 255) & ~(size_t)255;
        return p;
    };
    int nb = (N + 255) / 256;
    int*    cnt   = (int*)carve((size_t)(N + 1) * sizeof(int));
    int*    off   = (int*)carve((size_t)(N + 1) * sizeof(int));
    int*    bsum  = (int*)carve((size_t)nb * sizeof(int));
    int*    bbase = (int*)carve((size_t)nb * sizeof(int));
    int*    rank  = (int*)carve((size_t)E * sizeof(int));
    int*    csr   = (int*)carve((size_t)E * sizeof(int));
    __half* h     = (__half*)carve((size_t)N * DF * sizeof(__half));
    short*  xhi   = (short*)carve((size_t)N * DF * sizeof(short));
    short*  xlo   = (short*)carve((size_t)N * DF * sizeof(short));
    short*  whi   = (short*)carve((size_t)NLAYERS * DF * DF * sizeof(short));
    short*  wlo   = (short*)carve((size_t)NLAYERS * DF * DF * sizeof(short));

    // ---- CSR build + W split ----
    hipMemsetAsync(cnt, 0, (size_t)N * sizeof(int), stream);
    int nbE = (E + 255) / 256;
    int wt4 = NLAYERS * DF * DF / 4;
    int nbW = (wt4 + 255) / 256;
    prep_kernel<<<nbE + nbW, 256, 0, stream>>>(dst, cnt, rank, E, nbE, Ws, whi, wlo, wt4);
    partial_sum_kernel<<<nb, 256, 0, stream>>>(cnt, bsum, N);
    scan_bsums_kernel<<<1, 1024, 0, stream>>>(bsum, bbase, nb);
    scan_scatter_kernel<<<nb, 256, 0, stream>>>(cnt, bbase, off, N, E);
    fill_kernel<<<nbE, 256, 0, stream>>>(src, dst, off, rank, csr, E);

    int ggrid = (N + 63) / 64;
    int agrid = (N + 3) / 4;

    // layer 0 gemm: fp32 x (inline split) -> h
    gemm0_kernel<<<ggrid, 256, 0, stream>>>(x, whi, wlo, bs, h, N);

    // layers 1..4: agg(h) -> xhi/xlo (SiLU+split), gemm -> h; final agg -> out
    for (int layer = 1; layer < NLAYERS; ++layer) {
        agg_kernel<<<agrid, 256, 0, stream>>>(h, off, csr, out, xhi, xlo, N, 1);
        const short* whl = whi + (size_t)layer * DF * DF;
        const short* wll = wlo + (size_t)layer * DF * DF;
        const float* bl = bs + (size_t)layer * DF;
        gemm_mfma_kernel<<<ggrid, 256, 0, stream>>>(xhi, xlo, whl, wll, bl, h, N);
    }
    agg_kernel<<<agrid, 256, 0, stream>>>(h, off, csr, out, NULL, NULL, N, 0);
}

// Round 9
// 341.573 us; speedup vs baseline: 1.1485x; 1.0152x over previous
//
#include <hip/hip_runtime.h>
#include <hip/hip_bf16.h>
#include <hip/hip_fp16.h>
#include <math.h>

#define DF 128          // feature dim
#define NLAYERS 5

typedef __attribute__((ext_vector_type(8))) short bf16x8;
typedef __attribute__((ext_vector_type(4))) short short4v;
typedef __attribute__((ext_vector_type(4))) float f32x4;

// RTNE float -> bf16 bit pattern
__device__ inline unsigned short f2bf(float f) {
    unsigned u = __float_as_uint(f);
    u += 0x7FFF + ((u >> 16) & 1u);
    return (unsigned short)(u >> 16);
}
__device__ inline float bf2f(unsigned short s) {
    return __uint_as_float(((unsigned)s) << 16);
}

// packed fp16 max on raw bits (ROCm 7.2 lacks a viable fp16 __hmax2 overload)
__device__ inline unsigned pkmax(unsigned a, unsigned b) {
    unsigned d;
    asm("v_pk_max_f16 %0, %1, %2" : "=v"(d) : "v"(a), "v"(b));
    return d;
}
__device__ inline float h2f(unsigned short u) {
    __half_raw r; r.x = u;
    return __half2float(__half(r));
}
__device__ inline float silu(float v) {
    return v * (1.0f / (1.0f + __expf(-v)));
}

// split 8 consecutive floats into bf16 hi/lo fragments
__device__ inline void split8(const float* p, bf16x8& hi, bf16x8& lo) {
    float4 v0 = *reinterpret_cast<const float4*>(p);
    float4 v1 = *reinterpret_cast<const float4*>(p + 4);
    float f[8] = {v0.x, v0.y, v0.z, v0.w, v1.x, v1.y, v1.z, v1.w};
#pragma unroll
    for (int j = 0; j < 8; ++j) {
        unsigned short a = f2bf(f[j]);
        hi[j] = (short)a;
        lo[j] = (short)f2bf(f[j] - bf2f(a));
    }
}

// ---------------- zero cnt (runtime's small fillBuffer is ~43us; this is ~2us)

__global__ __launch_bounds__(256) void zero_kernel(int* __restrict__ p, int n) {
    int i = blockIdx.x * 256 + threadIdx.x;
    if (i < n) p[i] = 0;
}

// ---------------- prep: histogram+rank (blocks [0,nbE)) | split W (rest) -----

__global__ __launch_bounds__(256) void prep_kernel(const int* __restrict__ dst,
        int* __restrict__ cnt, int* __restrict__ rank, int E, int nbE,
        const float* __restrict__ Ws, short* __restrict__ whi,
        short* __restrict__ wlo, int wt4) {
    int b = blockIdx.x;
    int t = threadIdx.x;
    if (b < nbE) {
        int i = b * 256 + t;
        if (i < E) rank[i] = atomicAdd(&cnt[dst[i]], 1);
    } else {
        int i = (b - nbE) * 256 + t;
        if (i < wt4) {
            float4 v = reinterpret_cast<const float4*>(Ws)[i];
            short4v h, l;
            unsigned short a = f2bf(v.x); h.x = (short)a; l.x = (short)f2bf(v.x - bf2f(a));
            unsigned short bq = f2bf(v.y); h.y = (short)bq; l.y = (short)f2bf(v.y - bf2f(bq));
            unsigned short c = f2bf(v.z); h.z = (short)c; l.z = (short)f2bf(v.z - bf2f(c));
            unsigned short d = f2bf(v.w); h.w = (short)d; l.w = (short)f2bf(v.w - bf2f(d));
            reinterpret_cast<short4v*>(whi)[i] = h;
            reinterpret_cast<short4v*>(wlo)[i] = l;
        }
    }
}

// ---------------- CSR scan chain (2 kernels) ----------------

__global__ __launch_bounds__(256) void partial_sum_kernel(const int* __restrict__ cnt,
        int* __restrict__ bsum, int n) {
    __shared__ int red[256];
    int t = threadIdx.x;
    int i = blockIdx.x * 256 + t;
    red[t] = (i < n) ? cnt[i] : 0;
    __syncthreads();
    for (int d = 128; d > 0; d >>= 1) {
        if (t < d) red[t] += red[t + d];
        __syncthreads();
    }
    if (t == 0) bsum[blockIdx.x] = red[0];
}

// each block: (1) scans all nb (<=256) block sums in LDS to get its base,
// (2) scans its own 256 cnt values, writes exclusive offsets.
__global__ __launch_bounds__(256) void scan_scatter_kernel(const int* __restrict__ cnt,
        const int* __restrict__ bsum, int* __restrict__ off, int n, int E, int nb) {
    __shared__ int sb[256];
    __shared__ int s[256];
    int t = threadIdx.x;
    // scan of block sums
    int bv = (t < nb) ? bsum[t] : 0;
    sb[t] = bv;
    __syncthreads();
    for (int d = 1; d < 256; d <<= 1) {
        int u = (t >= d) ? sb[t - d] : 0;
        __syncthreads();
        sb[t] += u;
        __syncthreads();
    }
    int base = (blockIdx.x > 0) ? sb[blockIdx.x - 1] : 0;
    // own 256-element scan
    int i = blockIdx.x * 256 + t;
    int v = (i < n) ? cnt[i] : 0;
    s[t] = v;
    __syncthreads();
    for (int d = 1; d < 256; d <<= 1) {
        int u = (t >= d) ? s[t - d] : 0;
        __syncthreads();
        s[t] += u;
        __syncthreads();
    }
    int excl = s[t] - v + base;
    if (i < n) off[i] = excl;
    if (blockIdx.x == 0 && t == 0) off[n] = E;
}

// ---------------- fused: CSR fill (blocks [0,nbE)) | layer-0 GEMM (rest) ------
// Independent work co-scheduled to overlap scatter-bound fill with MFMA gemm0.

__global__ __launch_bounds__(256, 3) void fill_gemm0_kernel(
        const int* __restrict__ src, const int* __restrict__ dst,
        const int* __restrict__ off, const int* __restrict__ rank,
        int* __restrict__ csr, int E, int nbE,
        const float* __restrict__ x,
        const short* __restrict__ whi, const short* __restrict__ wlo,
        const float* __restrict__ bias, __half* __restrict__ h, int n) {
    if (blockIdx.x < nbE) {
        int i = blockIdx.x * 256 + threadIdx.x;
        if (i < E) csr[off[dst[i]] + rank[i]] = src[i];
        return;
    }
    int bid = blockIdx.x - nbE;

    int wave = threadIdx.x >> 6;
    int lane = threadIdx.x & 63;
    int wm = wave >> 1;
    int wn = wave & 1;
    int m0 = bid * 64 + wm * 32;
    int n0 = wn * 64;
    int lr = lane & 15;
    int lk = lane >> 4;

    f32x4 acc[2][4];
#pragma unroll
    for (int mt = 0; mt < 2; ++mt)
#pragma unroll
        for (int nt = 0; nt < 4; ++nt) {
            float bv = bias[n0 + nt * 16 + lr];
            acc[mt][nt] = (f32x4){bv, bv, bv, bv};
        }

    int rowA0 = min(m0 + lr, n - 1);
    int rowA1 = min(m0 + 16 + lr, n - 1);

#pragma unroll
    for (int ks = 0; ks < 4; ++ks) {
        int ko = ks * 32 + lk * 8;
        bf16x8 a0h, a0l, a1h, a1l;
        split8(x + (size_t)rowA0 * DF + ko, a0h, a0l);
        split8(x + (size_t)rowA1 * DF + ko, a1h, a1l);
#pragma unroll
        for (int nt = 0; nt < 4; ++nt) {
            int ncol = n0 + nt * 16 + lr;
            bf16x8 bh = *(const bf16x8*)(whi + ncol * DF + ko);
            bf16x8 bl = *(const bf16x8*)(wlo + ncol * DF + ko);
            acc[0][nt] = __builtin_amdgcn_mfma_f32_16x16x32_bf16(a0h, bh, acc[0][nt], 0, 0, 0);
            acc[0][nt] = __builtin_amdgcn_mfma_f32_16x16x32_bf16(a0l, bh, acc[0][nt], 0, 0, 0);
            acc[0][nt] = __builtin_amdgcn_mfma_f32_16x16x32_bf16(a0h, bl, acc[0][nt], 0, 0, 0);
            acc[1][nt] = __builtin_amdgcn_mfma_f32_16x16x32_bf16(a1h, bh, acc[1][nt], 0, 0, 0);
            acc[1][nt] = __builtin_amdgcn_mfma_f32_16x16x32_bf16(a1l, bh, acc[1][nt], 0, 0, 0);
            acc[1][nt] = __builtin_amdgcn_mfma_f32_16x16x32_bf16(a1h, bl, acc[1][nt], 0, 0, 0);
        }
    }

#pragma unroll
    for (int mt = 0; mt < 2; ++mt) {
        int rbase = m0 + mt * 16 + lk * 4;
#pragma unroll
        for (int j = 0; j < 4; ++j) {
            int r = rbase + j;
            if (r < n) {
#pragma unroll
                for (int nt = 0; nt < 4; ++nt)
                    h[(size_t)r * DF + n0 + nt * 16 + lr] = __float2half(acc[mt][nt][j]);
            }
        }
    }
}

// ---------------- GEMM via MFMA (bf16 hi/lo inputs from agg) ----------

__global__ __launch_bounds__(256, 3) void gemm_mfma_kernel(
        const short* __restrict__ xhi, const short* __restrict__ xlo,
        const short* __restrict__ whi, const short* __restrict__ wlo,
        const float* __restrict__ bias, __half* __restrict__ h, int n) {
    int wave = threadIdx.x >> 6;
    int lane = threadIdx.x & 63;
    int wm = wave >> 1;
    int wn = wave & 1;
    int m0 = blockIdx.x * 64 + wm * 32;
    int n0 = wn * 64;
    int lr = lane & 15;
    int lk = lane >> 4;

    f32x4 acc[2][4];
#pragma unroll
    for (int mt = 0; mt < 2; ++mt)
#pragma unroll
        for (int nt = 0; nt < 4; ++nt) {
            float bv = bias[n0 + nt * 16 + lr];
            acc[mt][nt] = (f32x4){bv, bv, bv, bv};
        }

    int rowA0 = min(m0 + lr, n - 1);
    int rowA1 = min(m0 + 16 + lr, n - 1);

#pragma unroll
    for (int ks = 0; ks < 4; ++ks) {
        int ko = ks * 32 + lk * 8;
        bf16x8 a0h = *(const bf16x8*)(xhi + (size_t)rowA0 * DF + ko);
        bf16x8 a0l = *(const bf16x8*)(xlo + (size_t)rowA0 * DF + ko);
        bf16x8 a1h = *(const bf16x8*)(xhi + (size_t)rowA1 * DF + ko);
        bf16x8 a1l = *(const bf16x8*)(xlo + (size_t)rowA1 * DF + ko);
#pragma unroll
        for (int nt = 0; nt < 4; ++nt) {
            int ncol = n0 + nt * 16 + lr;
            bf16x8 bh = *(const bf16x8*)(whi + ncol * DF + ko);
            bf16x8 bl = *(const bf16x8*)(wlo + ncol * DF + ko);
            acc[0][nt] = __builtin_amdgcn_mfma_f32_16x16x32_bf16(a0h, bh, acc[0][nt], 0, 0, 0);
            acc[0][nt] = __builtin_amdgcn_mfma_f32_16x16x32_bf16(a0l, bh, acc[0][nt], 0, 0, 0);
            acc[0][nt] = __builtin_amdgcn_mfma_f32_16x16x32_bf16(a0h, bl, acc[0][nt], 0, 0, 0);
            acc[1][nt] = __builtin_amdgcn_mfma_f32_16x16x32_bf16(a1h, bh, acc[1][nt], 0, 0, 0);
            acc[1][nt] = __builtin_amdgcn_mfma_f32_16x16x32_bf16(a1l, bh, acc[1][nt], 0, 0, 0);
            acc[1][nt] = __builtin_amdgcn_mfma_f32_16x16x32_bf16(a1h, bl, acc[1][nt], 0, 0, 0);
        }
    }

#pragma unroll
    for (int mt = 0; mt < 2; ++mt) {
        int rbase = m0 + mt * 16 + lk * 4;
#pragma unroll
        for (int j = 0; j < 4; ++j) {
            int r = rbase + j;
            if (r < n) {
#pragma unroll
                for (int nt = 0; nt < 4; ++nt)
                    h[(size_t)r * DF + n0 + nt * 16 + lr] = __float2half(acc[mt][nt][j]);
            }
        }
    }
}

// ---------------- Aggregation (fp16 gather, 16 edges in flight per wave) ------

__global__ __launch_bounds__(256) void agg_kernel(const __half* __restrict__ hin,
        const int* __restrict__ off, const int* __restrict__ csr,
        float* __restrict__ out, short* __restrict__ ohi, short* __restrict__ olo,
        int n, int split) {
    int wid = threadIdx.x >> 6;
    int lane = threadIdx.x & 63;
    int node = blockIdx.x * 4 + wid;
    if (node >= n) return;

    int hf = lane >> 5;          // edge parity
    int l = lane & 31;           // uint2 column within 256B row
    const uint2* h2 = (const uint2*)hin;

    int beg = off[node];
    int end = off[node + 1];

    unsigned m0 = 0xFC00FC00u;   // packed {-inf,-inf}
    unsigned m1 = 0xFC00FC00u;

    int e1 = end - 1;
    for (int k = beg; k < end; k += 16) {
        int k0 = k + hf;
        int i0 = min(k0,      e1), i1 = min(k0 + 2,  e1);
        int i2 = min(k0 + 4,  e1), i3 = min(k0 + 6,  e1);
        int i4 = min(k0 + 8,  e1), i5 = min(k0 + 10, e1);
        int i6 = min(k0 + 12, e1), i7 = min(k0 + 14, e1);
        int s0 = csr[i0], s1 = csr[i1], s2 = csr[i2], s3 = csr[i3];
        int s4 = csr[i4], s5 = csr[i5], s6 = csr[i6], s7 = csr[i7];
        uint2 a0 = h2[s0 * 32 + l];
        uint2 a1 = h2[s1 * 32 + l];
        uint2 a2 = h2[s2 * 32 + l];
        uint2 a3 = h2[s3 * 32 + l];
        uint2 a4 = h2[s4 * 32 + l];
        uint2 a5 = h2[s5 * 32 + l];
        uint2 a6 = h2[s6 * 32 + l];
        uint2 a7 = h2[s7 * 32 + l];
        m0 = pkmax(m0, pkmax(pkmax(pkmax(a0.x, a1.x), pkmax(a2.x, a3.x)),
                             pkmax(pkmax(a4.x, a5.x), pkmax(a6.x, a7.x))));
        m1 = pkmax(m1, pkmax(pkmax(pkmax(a0.y, a1.y), pkmax(a2.y, a3.y)),
                             pkmax(pkmax(a4.y, a5.y), pkmax(a6.y, a7.y))));
    }

    // combine edge-parity halves (lane i <-> lane i^32)
    m0 = pkmax(m0, (unsigned)__shfl_xor((int)m0, 32));
    m1 = pkmax(m1, (unsigned)__shfl_xor((int)m1, 32));

    if (hf != 0) return;

    float f0 = h2f((unsigned short)(m0 & 0xFFFF));
    float f1 = h2f((unsigned short)(m0 >> 16));
    float f2 = h2f((unsigned short)(m1 & 0xFFFF));
    float f3 = h2f((unsigned short)(m1 >> 16));
    if (beg == end) { f0 = f1 = f2 = f3 = 0.0f; }

    if (split) {
        f0 = silu(f0); f1 = silu(f1); f2 = silu(f2); f3 = silu(f3);
        short4v hv, lv;
        unsigned short a = f2bf(f0); hv.x = (short)a; lv.x = (short)f2bf(f0 - bf2f(a));
        unsigned short b = f2bf(f1); hv.y = (short)b; lv.y = (short)f2bf(f1 - bf2f(b));
        unsigned short c = f2bf(f2); hv.z = (short)c; lv.z = (short)f2bf(f2 - bf2f(c));
        unsigned short d = f2bf(f3); hv.w = (short)d; lv.w = (short)f2bf(f3 - bf2f(d));
        *reinterpret_cast<short4v*>(ohi + (size_t)node * DF + l * 4) = hv;
        *reinterpret_cast<short4v*>(olo + (size_t)node * DF + l * 4) = lv;
    } else {
        float4 v = make_float4(f0, f1, f2, f3);
        reinterpret_cast<float4*>(out)[node * 32 + l] = v;
    }
}

// ---------------- Launch ----------------

extern "C" void kernel_launch(void* const* d_in, const int* in_sizes, int n_in,
                              void* d_out, int out_size, void* d_ws, size_t ws_size,
                              hipStream_t stream) {
    const float* x  = (const float*)d_in[0];
    const int*   ei = (const int*)d_in[1];
    const float* Ws = (const float*)d_in[2];
    const float* bs = (const float*)d_in[3];
    float* out = (float*)d_out;

    int N = in_sizes[0] / DF;
    int E = in_sizes[1] / 2;
    const int* src = ei;
    const int* dst = ei + E;

    char* w = (char*)d_ws;
    auto carve = [&](size_t bytes) {
        char* p = w;
        w += (bytes + 255) & ~(size_t)255;
        return p;
    };
    int nb = (N + 255) / 256;
    int*    cnt   = (int*)carve((size_t)(N + 1) * sizeof(int));
    int*    off   = (int*)carve((size_t)(N + 1) * sizeof(int));
    int*    bsum  = (int*)carve((size_t)nb * sizeof(int));
    int*    rank  = (int*)carve((size_t)E * sizeof(int));
    int*    csr   = (int*)carve((size_t)E * sizeof(int));
    __half* h     = (__half*)carve((size_t)N * DF * sizeof(__half));
    short*  xhi   = (short*)carve((size_t)N * DF * sizeof(short));
    short*  xlo   = (short*)carve((size_t)N * DF * sizeof(short));
    short*  whi   = (short*)carve((size_t)NLAYERS * DF * DF * sizeof(short));
    short*  wlo   = (short*)carve((size_t)NLAYERS * DF * DF * sizeof(short));

    int nbE = (E + 255) / 256;
    int wt4 = NLAYERS * DF * DF / 4;
    int nbW = (wt4 + 255) / 256;
    int ggrid = (N + 63) / 64;
    int agrid = (N + 3) / 4;

    // ---- CSR build + W split (zero via own kernel; runtime small-fill is 43us)
    zero_kernel<<<nb, 256, 0, stream>>>(cnt, N);
    prep_kernel<<<nbE + nbW, 256, 0, stream>>>(dst, cnt, rank, E, nbE, Ws, whi, wlo, wt4);
    partial_sum_kernel<<<nb, 256, 0, stream>>>(cnt, bsum, N);
    scan_scatter_kernel<<<nb, 256, 0, stream>>>(cnt, bsum, off, N, E, nb);

    // ---- CSR fill co-launched with layer-0 gemm (independent work) ----
    fill_gemm0_kernel<<<nbE + ggrid, 256, 0, stream>>>(
        src, dst, off, rank, csr, E, nbE, x, whi, wlo, bs, h, N);

    // ---- layers 1..4: agg(h) -> xhi/xlo (SiLU+split), gemm -> h; final agg ----
    for (int layer = 1; layer < NLAYERS; ++layer) {
        agg_kernel<<<agrid, 256, 0, stream>>>(h, off, csr, out, xhi, xlo, N, 1);
        const short* whl = whi + (size_t)layer * DF * DF;
        const short* wll = wlo + (size_t)layer * DF * DF;
        const float* bl = bs + (size_t)layer * DF;
        gemm_mfma_kernel<<<ggrid, 256, 0, stream>>>(xhi, xlo, whl, wll, bl, h, N);
    }
    agg_kernel<<<agrid, 256, 0, stream>>>(h, off, csr, out, NULL, NULL, N, 0);
}

// Round 10
// 332.298 us; speedup vs baseline: 1.1805x; 1.0279x over previous
//
#include <hip/hip_runtime.h>
#include <hip/hip_bf16.h>
#include <hip/hip_fp16.h>
#include <math.h>

#define DF 128          // feature dim
#define NLAYERS 5

typedef __attribute__((ext_vector_type(8))) _Float16 f16x8;
typedef __attribute__((ext_vector_type(4))) _Float16 f16x4;
typedef __attribute__((ext_vector_type(4))) float f32x4;

// packed fp16 max on raw bits (ROCm 7.2 lacks a viable fp16 __hmax2 overload)
__device__ inline unsigned pkmax(unsigned a, unsigned b) {
    unsigned d;
    asm("v_pk_max_f16 %0, %1, %2" : "=v"(d) : "v"(a), "v"(b));
    return d;
}
__device__ inline float h2f(unsigned short u) {
    __half_raw r; r.x = u;
    return __half2float(__half(r));
}
__device__ inline float silu(float v) {
    return v * (1.0f / (1.0f + __expf(-v)));
}

// split 8 consecutive fp32 into fp16 hi + fp16 lo (hi+lo ~ 2^-22 accurate)
__device__ inline void split8f(const float* p, f16x8& hi, f16x8& lo) {
    float4 v0 = *reinterpret_cast<const float4*>(p);
    float4 v1 = *reinterpret_cast<const float4*>(p + 4);
    float f[8] = {v0.x, v0.y, v0.z, v0.w, v1.x, v1.y, v1.z, v1.w};
#pragma unroll
    for (int j = 0; j < 8; ++j) {
        _Float16 a = (_Float16)f[j];
        hi[j] = a;
        lo[j] = (_Float16)(f[j] - (float)a);
    }
}

// ---------------- zero cnt ----------------

__global__ __launch_bounds__(256) void zero_kernel(int* __restrict__ p, int n) {
    int i = blockIdx.x * 256 + threadIdx.x;
    if (i < n) p[i] = 0;
}

// ---------------- prep: histogram+rank (blocks [0,nbE)) | W->fp16 pair (rest) --

__global__ __launch_bounds__(256) void prep_kernel(const int* __restrict__ dst,
        int* __restrict__ cnt, unsigned short* __restrict__ rank, int E, int nbE,
        const float* __restrict__ Ws, _Float16* __restrict__ whf,
        _Float16* __restrict__ wlf, int wt4) {
    int b = blockIdx.x;
    int t = threadIdx.x;
    if (b < nbE) {
        int i = b * 256 + t;
        if (i < E) rank[i] = (unsigned short)atomicAdd(&cnt[dst[i]], 1);
    } else {
        int i = (b - nbE) * 256 + t;
        if (i < wt4) {
            float4 v = reinterpret_cast<const float4*>(Ws)[i];
            float f[4] = {v.x, v.y, v.z, v.w};
            f16x4 h, l;
#pragma unroll
            for (int j = 0; j < 4; ++j) {
                _Float16 a = (_Float16)f[j];
                h[j] = a;
                l[j] = (_Float16)(f[j] - (float)a);
            }
            reinterpret_cast<f16x4*>(whf)[i] = h;
            reinterpret_cast<f16x4*>(wlf)[i] = l;
        }
    }
}

// ---------------- CSR scan chain ----------------

__global__ __launch_bounds__(256) void partial_sum_kernel(const int* __restrict__ cnt,
        int* __restrict__ bsum, int n) {
    __shared__ int red[256];
    int t = threadIdx.x;
    int i = blockIdx.x * 256 + t;
    red[t] = (i < n) ? cnt[i] : 0;
    __syncthreads();
    for (int d = 128; d > 0; d >>= 1) {
        if (t < d) red[t] += red[t + d];
        __syncthreads();
    }
    if (t == 0) bsum[blockIdx.x] = red[0];
}

__global__ __launch_bounds__(256) void scan_scatter_kernel(const int* __restrict__ cnt,
        const int* __restrict__ bsum, int* __restrict__ off, int n, int E, int nb) {
    __shared__ int sb[256];
    __shared__ int s[256];
    int t = threadIdx.x;
    int bv = (t < nb) ? bsum[t] : 0;
    sb[t] = bv;
    __syncthreads();
    for (int d = 1; d < 256; d <<= 1) {
        int u = (t >= d) ? sb[t - d] : 0;
        __syncthreads();
        sb[t] += u;
        __syncthreads();
    }
    int base = (blockIdx.x > 0) ? sb[blockIdx.x - 1] : 0;
    int i = blockIdx.x * 256 + t;
    int v = (i < n) ? cnt[i] : 0;
    s[t] = v;
    __syncthreads();
    for (int d = 1; d < 256; d <<= 1) {
        int u = (t >= d) ? s[t - d] : 0;
        __syncthreads();
        s[t] += u;
        __syncthreads();
    }
    int excl = s[t] - v + base;
    if (i < n) off[i] = excl;
    if (blockIdx.x == 0 && t == 0) off[n] = E;
}

// ---------------- fused: CSR fill (ushort) | layer-0 GEMM f16 ----------------

__global__ __launch_bounds__(256, 3) void fill_gemm0_kernel(
        const int* __restrict__ src, const int* __restrict__ dst,
        const int* __restrict__ off, const unsigned short* __restrict__ rank,
        unsigned short* __restrict__ csr, int E, int nbE,
        const float* __restrict__ x,
        const _Float16* __restrict__ whf, const _Float16* __restrict__ wlf,
        const float* __restrict__ bias, __half* __restrict__ h, int n) {
    if (blockIdx.x < nbE) {
        int i = blockIdx.x * 256 + threadIdx.x;
        if (i < E) csr[off[dst[i]] + (int)rank[i]] = (unsigned short)src[i];
        return;
    }
    int bid = blockIdx.x - nbE;

    int wave = threadIdx.x >> 6;
    int lane = threadIdx.x & 63;
    int wm = wave >> 1;
    int wn = wave & 1;
    int m0 = bid * 64 + wm * 32;
    int n0 = wn * 64;
    int lr = lane & 15;
    int lk = lane >> 4;

    f32x4 acc[2][4];
#pragma unroll
    for (int mt = 0; mt < 2; ++mt)
#pragma unroll
        for (int nt = 0; nt < 4; ++nt) {
            float bv = bias[n0 + nt * 16 + lr];
            acc[mt][nt] = (f32x4){bv, bv, bv, bv};
        }

    int rowA0 = min(m0 + lr, n - 1);
    int rowA1 = min(m0 + 16 + lr, n - 1);

#pragma unroll
    for (int ks = 0; ks < 4; ++ks) {
        int ko = ks * 32 + lk * 8;
        f16x8 a0h, a0l, a1h, a1l;
        split8f(x + (size_t)rowA0 * DF + ko, a0h, a0l);
        split8f(x + (size_t)rowA1 * DF + ko, a1h, a1l);
#pragma unroll
        for (int nt = 0; nt < 4; ++nt) {
            int ncol = n0 + nt * 16 + lr;
            f16x8 wh = *(const f16x8*)(whf + ncol * DF + ko);
            f16x8 wl = *(const f16x8*)(wlf + ncol * DF + ko);
            acc[0][nt] = __builtin_amdgcn_mfma_f32_16x16x32_f16(a0h, wh, acc[0][nt], 0, 0, 0);
            acc[0][nt] = __builtin_amdgcn_mfma_f32_16x16x32_f16(a0l, wh, acc[0][nt], 0, 0, 0);
            acc[0][nt] = __builtin_amdgcn_mfma_f32_16x16x32_f16(a0h, wl, acc[0][nt], 0, 0, 0);
            acc[1][nt] = __builtin_amdgcn_mfma_f32_16x16x32_f16(a1h, wh, acc[1][nt], 0, 0, 0);
            acc[1][nt] = __builtin_amdgcn_mfma_f32_16x16x32_f16(a1l, wh, acc[1][nt], 0, 0, 0);
            acc[1][nt] = __builtin_amdgcn_mfma_f32_16x16x32_f16(a1h, wl, acc[1][nt], 0, 0, 0);
        }
    }

#pragma unroll
    for (int mt = 0; mt < 2; ++mt) {
        int rbase = m0 + mt * 16 + lk * 4;
#pragma unroll
        for (int j = 0; j < 4; ++j) {
            int r = rbase + j;
            if (r < n) {
#pragma unroll
                for (int nt = 0; nt < 4; ++nt)
                    h[(size_t)r * DF + n0 + nt * 16 + lr] = __float2half(acc[mt][nt][j]);
            }
        }
    }
}

// ---------------- GEMM layers 1-4: A = fp16 x (exact), B = fp16 W pair --------

__global__ __launch_bounds__(256, 3) void gemm_f16_kernel(
        const _Float16* __restrict__ xf,
        const _Float16* __restrict__ whf, const _Float16* __restrict__ wlf,
        const float* __restrict__ bias, __half* __restrict__ h, int n) {
    int wave = threadIdx.x >> 6;
    int lane = threadIdx.x & 63;
    int wm = wave >> 1;
    int wn = wave & 1;
    int m0 = blockIdx.x * 64 + wm * 32;
    int n0 = wn * 64;
    int lr = lane & 15;
    int lk = lane >> 4;

    f32x4 acc[2][4];
#pragma unroll
    for (int mt = 0; mt < 2; ++mt)
#pragma unroll
        for (int nt = 0; nt < 4; ++nt) {
            float bv = bias[n0 + nt * 16 + lr];
            acc[mt][nt] = (f32x4){bv, bv, bv, bv};
        }

    int rowA0 = min(m0 + lr, n - 1);
    int rowA1 = min(m0 + 16 + lr, n - 1);

#pragma unroll
    for (int ks = 0; ks < 4; ++ks) {
        int ko = ks * 32 + lk * 8;
        f16x8 a0 = *(const f16x8*)(xf + (size_t)rowA0 * DF + ko);
        f16x8 a1 = *(const f16x8*)(xf + (size_t)rowA1 * DF + ko);
#pragma unroll
        for (int nt = 0; nt < 4; ++nt) {
            int ncol = n0 + nt * 16 + lr;
            f16x8 wh = *(const f16x8*)(whf + ncol * DF + ko);
            f16x8 wl = *(const f16x8*)(wlf + ncol * DF + ko);
            acc[0][nt] = __builtin_amdgcn_mfma_f32_16x16x32_f16(a0, wh, acc[0][nt], 0, 0, 0);
            acc[0][nt] = __builtin_amdgcn_mfma_f32_16x16x32_f16(a0, wl, acc[0][nt], 0, 0, 0);
            acc[1][nt] = __builtin_amdgcn_mfma_f32_16x16x32_f16(a1, wh, acc[1][nt], 0, 0, 0);
            acc[1][nt] = __builtin_amdgcn_mfma_f32_16x16x32_f16(a1, wl, acc[1][nt], 0, 0, 0);
        }
    }

#pragma unroll
    for (int mt = 0; mt < 2; ++mt) {
        int rbase = m0 + mt * 16 + lk * 4;
#pragma unroll
        for (int j = 0; j < 4; ++j) {
            int r = rbase + j;
            if (r < n) {
#pragma unroll
                for (int nt = 0; nt < 4; ++nt)
                    h[(size_t)r * DF + n0 + nt * 16 + lr] = __float2half(acc[mt][nt][j]);
            }
        }
    }
}

// ---------------- Aggregation (fp16 gather, 16 edges in flight per wave) ------
// split==1: SiLU, write single fp16 x for next layer. split==0: fp32 to d_out.

__global__ __launch_bounds__(256) void agg_kernel(const __half* __restrict__ hin,
        const int* __restrict__ off, const unsigned short* __restrict__ csr,
        float* __restrict__ out, _Float16* __restrict__ xf, int n, int split) {
    int wid = threadIdx.x >> 6;
    int lane = threadIdx.x & 63;
    int node = blockIdx.x * 4 + wid;
    if (node >= n) return;

    int hf = lane >> 5;          // edge parity
    int l = lane & 31;           // uint2 column within 256B row
    const uint2* h2 = (const uint2*)hin;

    int beg = off[node];
    int end = off[node + 1];

    unsigned m0 = 0xFC00FC00u;   // packed {-inf,-inf}
    unsigned m1 = 0xFC00FC00u;

    int e1 = end - 1;
    for (int k = beg; k < end; k += 16) {
        int k0 = k + hf;
        int i0 = min(k0,      e1), i1 = min(k0 + 2,  e1);
        int i2 = min(k0 + 4,  e1), i3 = min(k0 + 6,  e1);
        int i4 = min(k0 + 8,  e1), i5 = min(k0 + 10, e1);
        int i6 = min(k0 + 12, e1), i7 = min(k0 + 14, e1);
        int s0 = csr[i0], s1 = csr[i1], s2 = csr[i2], s3 = csr[i3];
        int s4 = csr[i4], s5 = csr[i5], s6 = csr[i6], s7 = csr[i7];
        uint2 a0 = h2[s0 * 32 + l];
        uint2 a1 = h2[s1 * 32 + l];
        uint2 a2 = h2[s2 * 32 + l];
        uint2 a3 = h2[s3 * 32 + l];
        uint2 a4 = h2[s4 * 32 + l];
        uint2 a5 = h2[s5 * 32 + l];
        uint2 a6 = h2[s6 * 32 + l];
        uint2 a7 = h2[s7 * 32 + l];
        m0 = pkmax(m0, pkmax(pkmax(pkmax(a0.x, a1.x), pkmax(a2.x, a3.x)),
                             pkmax(pkmax(a4.x, a5.x), pkmax(a6.x, a7.x))));
        m1 = pkmax(m1, pkmax(pkmax(pkmax(a0.y, a1.y), pkmax(a2.y, a3.y)),
                             pkmax(pkmax(a4.y, a5.y), pkmax(a6.y, a7.y))));
    }

    m0 = pkmax(m0, (unsigned)__shfl_xor((int)m0, 32));
    m1 = pkmax(m1, (unsigned)__shfl_xor((int)m1, 32));

    if (hf != 0) return;

    float f0 = h2f((unsigned short)(m0 & 0xFFFF));
    float f1 = h2f((unsigned short)(m0 >> 16));
    float f2 = h2f((unsigned short)(m1 & 0xFFFF));
    float f3 = h2f((unsigned short)(m1 >> 16));
    if (beg == end) { f0 = f1 = f2 = f3 = 0.0f; }

    if (split) {
        f0 = silu(f0); f1 = silu(f1); f2 = silu(f2); f3 = silu(f3);
        f16x4 v = { (_Float16)f0, (_Float16)f1, (_Float16)f2, (_Float16)f3 };
        *reinterpret_cast<f16x4*>(xf + (size_t)node * DF + l * 4) = v;
    } else {
        float4 v = make_float4(f0, f1, f2, f3);
        reinterpret_cast<float4*>(out)[node * 32 + l] = v;
    }
}

// ---------------- Launch ----------------

extern "C" void kernel_launch(void* const* d_in, const int* in_sizes, int n_in,
                              void* d_out, int out_size, void* d_ws, size_t ws_size,
                              hipStream_t stream) {
    const float* x  = (const float*)d_in[0];
    const int*   ei = (const int*)d_in[1];
    const float* Ws = (const float*)d_in[2];
    const float* bs = (const float*)d_in[3];
    float* out = (float*)d_out;

    int N = in_sizes[0] / DF;
    int E = in_sizes[1] / 2;
    const int* src = ei;
    const int* dst = ei + E;

    char* w = (char*)d_ws;
    auto carve = [&](size_t bytes) {
        char* p = w;
        w += (bytes + 255) & ~(size_t)255;
        return p;
    };
    int nb = (N + 255) / 256;
    int*            cnt  = (int*)carve((size_t)(N + 1) * sizeof(int));
    int*            off  = (int*)carve((size_t)(N + 1) * sizeof(int));
    int*            bsum = (int*)carve((size_t)nb * sizeof(int));
    unsigned short* rank = (unsigned short*)carve((size_t)E * sizeof(unsigned short));
    unsigned short* csr  = (unsigned short*)carve((size_t)E * sizeof(unsigned short));
    __half*         h    = (__half*)carve((size_t)N * DF * sizeof(__half));
    _Float16*       xf   = (_Float16*)carve((size_t)N * DF * sizeof(_Float16));
    _Float16*       whf  = (_Float16*)carve((size_t)NLAYERS * DF * DF * sizeof(_Float16));
    _Float16*       wlf  = (_Float16*)carve((size_t)NLAYERS * DF * DF * sizeof(_Float16));

    int nbE = (E + 255) / 256;
    int wt4 = NLAYERS * DF * DF / 4;
    int nbW = (wt4 + 255) / 256;
    int ggrid = (N + 63) / 64;
    int agrid = (N + 3) / 4;

    // ---- CSR build + W fp16-pair split ----
    zero_kernel<<<nb, 256, 0, stream>>>(cnt, N);
    prep_kernel<<<nbE + nbW, 256, 0, stream>>>(dst, cnt, rank, E, nbE, Ws, whf, wlf, wt4);
    partial_sum_kernel<<<nb, 256, 0, stream>>>(cnt, bsum, N);
    scan_scatter_kernel<<<nb, 256, 0, stream>>>(cnt, bsum, off, N, E, nb);

    // ---- CSR fill co-launched with layer-0 gemm ----
    fill_gemm0_kernel<<<nbE + ggrid, 256, 0, stream>>>(
        src, dst, off, rank, csr, E, nbE, x, whf, wlf, bs, h, N);

    // ---- layers 1..4: agg -> xf (SiLU, fp16), gemm -> h; final agg -> out ----
    for (int layer = 1; layer < NLAYERS; ++layer) {
        agg_kernel<<<agrid, 256, 0, stream>>>(h, off, csr, out, xf, N, 1);
        const _Float16* whl = whf + (size_t)layer * DF * DF;
        const _Float16* wll = wlf + (size_t)layer * DF * DF;
        const float* bl = bs + (size_t)layer * DF;
        gemm_f16_kernel<<<ggrid, 256, 0, stream>>>(xf, whl, wll, bl, h, N);
    }
    agg_kernel<<<agrid, 256, 0, stream>>>(h, off, csr, out, NULL, N, 0);
}